// Round 1
// baseline (353.075 us; speedup 1.0000x reference)
//
#include <hip/hip_runtime.h>

// GCN 2-layer, padded per-node CSR via single-pass atomic scatter.
//   out[c] = dinv[c] * ( h_s[c] + sum_{e: col=c} h_s[row_e] ) + b,  h_s=(X@W)*dinv
// R11: replaced {k_bin LDS-sort + k_bucket_sort} (≈5 passes over entries) with
// one k_bin pass: p = atomicAdd(&cursor[col],1); bentries[col*64+p] = row.
// Fixed CAP=64 slots/node (max in-degree ~45 for Poisson(16) over 100k nodes).
// start[] is implicit (node*64), cnt = cursor, dinv = rsqrt(cnt+1) inline.
// Messages bf16, accum fp32. Layer boundary h2 bf16 in d_out scratch.

#define CAP 64
#define BM 128
#define BK 32

__device__ __forceinline__ unsigned short f2bf(float f) {
    unsigned u = __builtin_bit_cast(unsigned, f);
    u = (u + 0x7FFF + ((u >> 16) & 1)) >> 16;  // RNE
    return (unsigned short)u;
}
__device__ __forceinline__ float bflo(unsigned u) {  // low bf16 of packed pair
    return __builtin_bit_cast(float, u << 16);
}
__device__ __forceinline__ float bfhi(unsigned u) {  // high bf16 of packed pair
    return __builtin_bit_cast(float, u & 0xFFFF0000u);
}

__global__ __launch_bounds__(256) void k_zero_i(int* __restrict__ p, int n) {
    int i = blockIdx.x * 256 + threadIdx.x;
    if (i < n) p[i] = 0;
}

// (A) single-pass binning: per edge, reserve a slot in the destination node's
// fixed 64-entry region and write the source row there. 4 edges/thread via
// int4 loads. Entries fill region sequentially -> gather reads are contiguous.
__global__ __launch_bounds__(256) void k_bin(const int* __restrict__ row,
                                             const int* __restrict__ col,
                                             int* __restrict__ cursor,
                                             int* __restrict__ bentries, int E) {
    int i0 = (blockIdx.x * 256 + threadIdx.x) * 4;
    if (i0 + 3 < E) {
        int4 r4 = *(const int4*)(row + i0);
        int4 c4 = *(const int4*)(col + i0);
        int p;
        p = atomicAdd(&cursor[c4.x], 1);
        if (p < CAP) bentries[(size_t)c4.x * CAP + p] = r4.x;
        p = atomicAdd(&cursor[c4.y], 1);
        if (p < CAP) bentries[(size_t)c4.y * CAP + p] = r4.y;
        p = atomicAdd(&cursor[c4.z], 1);
        if (p < CAP) bentries[(size_t)c4.z * CAP + p] = r4.z;
        p = atomicAdd(&cursor[c4.w], 1);
        if (p < CAP) bentries[(size_t)c4.w * CAP + p] = r4.w;
    } else {
        for (int i = i0; i < E; ++i) {
            int c = col[i], r = row[i];
            int p = atomicAdd(&cursor[c], 1);
            if (p < CAP) bentries[(size_t)c * CAP + p] = r;
        }
    }
}

// Tiled GEMM + row scale, fp32 input, bf16 output.
// Block = 256 threads -> BM=128 rows x 64 cols. K chunked by BK=32.
// Row scale dinv = rsqrt(deg+1) computed inline from the degree cursor.
__global__ __launch_bounds__(256) void k_gemm_f32in(
    const float* __restrict__ X, const float* __restrict__ W,
    const int* __restrict__ deg, unsigned short* __restrict__ outb,
    int N, int K) {
    __shared__ float Xs[BK][BM + 4];
    __shared__ float Ws[BK][64];
    int t = threadIdx.x;
    int bm = blockIdx.x * BM;
    int tm = t >> 4, tn = t & 15;

    float acc[8][4];
#pragma unroll
    for (int i = 0; i < 8; ++i)
#pragma unroll
        for (int j = 0; j < 4; ++j) acc[i][j] = 0.f;

    for (int kb = 0; kb < K; kb += BK) {
#pragma unroll
        for (int it = 0; it < 4; ++it) {
            int r = (t >> 3) + 32 * it;       // 0..127
            int grow = bm + r;
            int k4 = t & 7;                   // float4 index within BK
            float4 v = make_float4(0.f, 0.f, 0.f, 0.f);
            if (grow < N) v = *(const float4*)(X + (size_t)grow * K + kb + k4 * 4);
            Xs[k4 * 4 + 0][r] = v.x;
            Xs[k4 * 4 + 1][r] = v.y;
            Xs[k4 * 4 + 2][r] = v.z;
            Xs[k4 * 4 + 3][r] = v.w;
        }
#pragma unroll
        for (int it = 0; it < 2; ++it) {
            int idx = t + 256 * it;           // 0..511 float4s
            ((float4*)Ws)[idx] = ((const float4*)(W + (size_t)kb * 64))[idx];
        }
        __syncthreads();
#pragma unroll
        for (int k = 0; k < BK; ++k) {
            float4 xa = *(const float4*)&Xs[k][tm * 8];
            float4 xb = *(const float4*)&Xs[k][tm * 8 + 4];
            float4 w = *(const float4*)&Ws[k][tn * 4];
            float xs[8] = {xa.x, xa.y, xa.z, xa.w, xb.x, xb.y, xb.z, xb.w};
#pragma unroll
            for (int i = 0; i < 8; ++i) {
                acc[i][0] = fmaf(xs[i], w.x, acc[i][0]);
                acc[i][1] = fmaf(xs[i], w.y, acc[i][1]);
                acc[i][2] = fmaf(xs[i], w.z, acc[i][2]);
                acc[i][3] = fmaf(xs[i], w.w, acc[i][3]);
            }
        }
        __syncthreads();
    }
#pragma unroll
    for (int i = 0; i < 8; ++i) {
        int grow = bm + tm * 8 + i;
        if (grow < N) {
            float s = rsqrtf((float)deg[grow] + 1.0f);
            ushort4 v;
            v.x = f2bf(acc[i][0] * s);
            v.y = f2bf(acc[i][1] * s);
            v.z = f2bf(acc[i][2] * s);
            v.w = f2bf(acc[i][3] * s);
            *(ushort4*)(outb + (size_t)grow * 64 + tn * 4) = v;
        }
    }
}

// Tiled GEMM + row scale, bf16 input, bf16 output. Same tile shape.
__global__ __launch_bounds__(256) void k_gemm_bf16in(
    const unsigned short* __restrict__ Xb, const float* __restrict__ W,
    const int* __restrict__ deg, unsigned short* __restrict__ outb,
    int N, int K) {
    __shared__ float Xs[BK][BM + 4];
    __shared__ float Ws[BK][64];
    int t = threadIdx.x;
    int bm = blockIdx.x * BM;
    int tm = t >> 4, tn = t & 15;

    float acc[8][4];
#pragma unroll
    for (int i = 0; i < 8; ++i)
#pragma unroll
        for (int j = 0; j < 4; ++j) acc[i][j] = 0.f;

    for (int kb = 0; kb < K; kb += BK) {
        // 128 rows x 32 k bf16 = 512 uint4 (8 bf16 each); 2 per thread
#pragma unroll
        for (int it = 0; it < 2; ++it) {
            int idx = t * 2 + it;             // 0..511
            int r = idx >> 2;                 // 0..127
            int q = idx & 3;                  // 16B chunk: k = q*8..q*8+8
            int grow = bm + r;
            uint4 v = make_uint4(0u, 0u, 0u, 0u);
            if (grow < N) v = *(const uint4*)(Xb + (size_t)grow * K + kb + q * 8);
            int k0 = q * 8;
            Xs[k0 + 0][r] = bflo(v.x); Xs[k0 + 1][r] = bfhi(v.x);
            Xs[k0 + 2][r] = bflo(v.y); Xs[k0 + 3][r] = bfhi(v.y);
            Xs[k0 + 4][r] = bflo(v.z); Xs[k0 + 5][r] = bfhi(v.z);
            Xs[k0 + 6][r] = bflo(v.w); Xs[k0 + 7][r] = bfhi(v.w);
        }
#pragma unroll
        for (int it = 0; it < 2; ++it) {
            int idx = t + 256 * it;           // 0..511 float4s
            ((float4*)Ws)[idx] = ((const float4*)(W + (size_t)kb * 64))[idx];
        }
        __syncthreads();
#pragma unroll
        for (int k = 0; k < BK; ++k) {
            float4 xa = *(const float4*)&Xs[k][tm * 8];
            float4 xb = *(const float4*)&Xs[k][tm * 8 + 4];
            float4 w = *(const float4*)&Ws[k][tn * 4];
            float xs[8] = {xa.x, xa.y, xa.z, xa.w, xb.x, xb.y, xb.z, xb.w};
#pragma unroll
            for (int i = 0; i < 8; ++i) {
                acc[i][0] = fmaf(xs[i], w.x, acc[i][0]);
                acc[i][1] = fmaf(xs[i], w.y, acc[i][1]);
                acc[i][2] = fmaf(xs[i], w.z, acc[i][2]);
                acc[i][3] = fmaf(xs[i], w.w, acc[i][3]);
            }
        }
        __syncthreads();
    }
#pragma unroll
    for (int i = 0; i < 8; ++i) {
        int grow = bm + tm * 8 + i;
        if (grow < N) {
            float s = rsqrtf((float)deg[grow] + 1.0f);
            ushort4 v;
            v.x = f2bf(acc[i][0] * s);
            v.y = f2bf(acc[i][1] * s);
            v.z = f2bf(acc[i][2] * s);
            v.w = f2bf(acc[i][3] * s);
            *(ushort4*)(outb + (size_t)grow * 64 + tn * 4) = v;
        }
    }
}

// Gather-aggregate + fused postproc. 8 lanes/node; lane l owns channels
// [8l, 8l+8) as one uint4 (4 packed bf16 pairs). fp32 accumulate.
// acc init = src[node] (self loop). Entries at bentries[node*CAP .. +cnt).
// MLP-unrolled x8 (+x4 tail).
// mode 1: relu + bf16 out (dstq). mode 0: fp32 out (dstf).
__global__ __launch_bounds__(256) void k_gather(
    const uint4* __restrict__ srcq, const int* __restrict__ eros,
    const int* __restrict__ deg, const float* __restrict__ bias,
    float* __restrict__ dstf, uint4* __restrict__ dstq, int N, int mode) {
    int idx = blockIdx.x * 256 + threadIdx.x;
    int node = idx >> 3;
    if (node >= N) return;
    int l = idx & 7;

    uint4 sv = srcq[(size_t)node * 8 + l];  // self loop
    float a0 = bflo(sv.x), a1 = bfhi(sv.x);
    float a2 = bflo(sv.y), a3 = bfhi(sv.y);
    float a4 = bflo(sv.z), a5 = bfhi(sv.z);
    float a6 = bflo(sv.w), a7 = bfhi(sv.w);

    int cnt = deg[node];
    float sc = rsqrtf((float)cnt + 1.0f);
    if (cnt > CAP) cnt = CAP;  // safety clamp (never expected)
    int e = node * CAP;
    int eend = e + cnt;
    for (; e + 8 <= eend; e += 8) {
        uint4 v[8];
#pragma unroll
        for (int j = 0; j < 8; ++j) {
            int r = eros[e + j];
            v[j] = srcq[(size_t)r * 8 + l];
        }
#pragma unroll
        for (int j = 0; j < 8; ++j) {
            a0 += bflo(v[j].x); a1 += bfhi(v[j].x);
            a2 += bflo(v[j].y); a3 += bfhi(v[j].y);
            a4 += bflo(v[j].z); a5 += bfhi(v[j].z);
            a6 += bflo(v[j].w); a7 += bfhi(v[j].w);
        }
    }
    for (; e + 4 <= eend; e += 4) {
        uint4 v[4];
#pragma unroll
        for (int j = 0; j < 4; ++j) {
            int r = eros[e + j];
            v[j] = srcq[(size_t)r * 8 + l];
        }
#pragma unroll
        for (int j = 0; j < 4; ++j) {
            a0 += bflo(v[j].x); a1 += bfhi(v[j].x);
            a2 += bflo(v[j].y); a3 += bfhi(v[j].y);
            a4 += bflo(v[j].z); a5 += bfhi(v[j].z);
            a6 += bflo(v[j].w); a7 += bfhi(v[j].w);
        }
    }
    for (; e < eend; ++e) {
        int r = eros[e];
        uint4 v = srcq[(size_t)r * 8 + l];
        a0 += bflo(v.x); a1 += bfhi(v.x);
        a2 += bflo(v.y); a3 += bfhi(v.y);
        a4 += bflo(v.z); a5 += bfhi(v.z);
        a6 += bflo(v.w); a7 += bfhi(v.w);
    }
    const float4* bp = (const float4*)bias;
    float4 b0 = bp[l * 2], b1 = bp[l * 2 + 1];
    a0 = a0 * sc + b0.x; a1 = a1 * sc + b0.y;
    a2 = a2 * sc + b0.z; a3 = a3 * sc + b0.w;
    a4 = a4 * sc + b1.x; a5 = a5 * sc + b1.y;
    a6 = a6 * sc + b1.z; a7 = a7 * sc + b1.w;
    if (mode) {  // relu + bf16 pack
        a0 = fmaxf(a0, 0.f); a1 = fmaxf(a1, 0.f);
        a2 = fmaxf(a2, 0.f); a3 = fmaxf(a3, 0.f);
        a4 = fmaxf(a4, 0.f); a5 = fmaxf(a5, 0.f);
        a6 = fmaxf(a6, 0.f); a7 = fmaxf(a7, 0.f);
        uint4 o;
        o.x = (unsigned)f2bf(a0) | ((unsigned)f2bf(a1) << 16);
        o.y = (unsigned)f2bf(a2) | ((unsigned)f2bf(a3) << 16);
        o.z = (unsigned)f2bf(a4) | ((unsigned)f2bf(a5) << 16);
        o.w = (unsigned)f2bf(a6) | ((unsigned)f2bf(a7) << 16);
        dstq[(size_t)node * 8 + l] = o;
    } else {
        float4 o0 = make_float4(a0, a1, a2, a3);
        float4 o1 = make_float4(a4, a5, a6, a7);
        float4* d = (float4*)(dstf + (size_t)node * 64 + l * 8);
        d[0] = o0;
        d[1] = o1;
    }
}

extern "C" void kernel_launch(void* const* d_in, const int* in_sizes, int n_in,
                              void* d_out, int out_size, void* d_ws, size_t ws_size,
                              hipStream_t stream) {
    const float* x = (const float*)d_in[0];
    const int* ei = (const int*)d_in[1];  // int32 per harness contract, [2, E]
    const float* W1 = (const float*)d_in[2];
    const float* b1 = (const float*)d_in[3];
    const float* W2 = (const float*)d_in[4];
    const float* b2 = (const float*)d_in[5];

    int N = in_sizes[0] / 128;  // 100000
    int E = in_sizes[1] / 2;    // 1600000
    const int* row = ei;
    const int* col = ei + E;

    char* ws = (char*)d_ws;
    int* cursor = (int*)ws;                          // N ints @ 0 (in-degrees)
    int* bentries = (int*)(ws + (1 << 20));          // N*CAP ints @ 1 MB (25.6 MB)
    unsigned short* Ab = (unsigned short*)(ws + (28 << 20));  // N*64 bf16 @ 28 MB
    unsigned short* Hb = (unsigned short*)d_out;     // bf16 h2 scratch in d_out
    float* OUTF = (float*)d_out;                     // final fp32 output

    int gemmblk = (N + BM - 1) / BM;            // 782
    int binblk = (E / 4 + 255) / 256;           // 1563
    int gblk = (N * 8 + 255) / 256;             // 3125

    // --- CSR build (padded per-node regions; once, shared by both layers) ---
    k_zero_i<<<(N + 255) / 256, 256, 0, stream>>>(cursor, N);
    k_bin<<<binblk, 256, 0, stream>>>(row, col, cursor, bentries, E);

    // Layer 1: Ab = bf16((X@W1)*dinv); Hb = bf16(relu(gather(Ab)*dinv + b1))
    k_gemm_f32in<<<gemmblk, 256, 0, stream>>>(x, W1, cursor, Ab, N, 128);
    k_gather<<<gblk, 256, 0, stream>>>((const uint4*)Ab, bentries,
                                       cursor, b1, nullptr, (uint4*)Hb, N, 1);

    // Layer 2: Ab = bf16((Hb@W2)*dinv); d_out = gather(Ab)*dinv + b2 (fp32)
    k_gemm_bf16in<<<gemmblk, 256, 0, stream>>>(Hb, W2, cursor, Ab, N, 64);
    k_gather<<<gblk, 256, 0, stream>>>((const uint4*)Ab, bentries,
                                       cursor, b2, OUTF, nullptr, N, 0);
}

// Round 2
// 250.156 us; speedup vs baseline: 1.4114x; 1.4114x over previous
//
#include <hip/hip_runtime.h>

// GCN 2-layer, CSR-gather formulation, padded-bucket CSR build.
//   out[c] = dinv[c] * ( h_s[c] + sum_{e: col=c} h_s[row_e] ) + b,  h_s=(X@W)*dinv
// R12: restored R10 build chain (bucketed k_bin + k_bucket_sort) after R11's
// single-pass atomic scatter regressed 2.4x (WRITE_SIZE 97MB from 4B-scatter
// line amplification; k_bin 140us). Gather reworked: 4 lanes/node x 2 uint4
// (32B contiguous per lane), unroll 8/4/1 -> 2x per-lane MLP, half the waves,
// half the redundant index loads. Messages bf16, accum fp32.
// Requires N < 2^17. Integer inputs arrive as int32.

#define BKT_SH 7            // 128 nodes per bucket
#define BKT_CAP 4096        // region per bucket (counts ~2046 +- 45; huge margin)
#define CHUNK 6144          // edges per k_bin block
#define BM 128
#define BK 32

__device__ __forceinline__ unsigned short f2bf(float f) {
    unsigned u = __builtin_bit_cast(unsigned, f);
    u = (u + 0x7FFF + ((u >> 16) & 1)) >> 16;  // RNE
    return (unsigned short)u;
}
__device__ __forceinline__ float bflo(unsigned u) {  // low bf16 of packed pair
    return __builtin_bit_cast(float, u << 16);
}
__device__ __forceinline__ float bfhi(unsigned u) {  // high bf16 of packed pair
    return __builtin_bit_cast(float, u & 0xFFFF0000u);
}

__global__ __launch_bounds__(256) void k_zero_i(int* __restrict__ p, int n) {
    int i = blockIdx.x * 256 + threadIdx.x;
    if (i < n) p[i] = 0;
}

// (A) block-chunked binning: LDS hist -> LDS scan -> one count-reservation
// atomic per (block,bucket) -> LDS sort by bucket -> run-coalesced writes into
// fixed bucket region [bkt*CAP, (bkt+1)*CAP). cursor zero-init; ends = counts.
__global__ __launch_bounds__(256) void k_bin(const int* __restrict__ row,
                                             const int* __restrict__ col,
                                             int* __restrict__ cursor,
                                             unsigned* __restrict__ bentries,
                                             int E) {
    __shared__ unsigned sorted[CHUNK];        // 24 KB packed entries, bucket order
    __shared__ unsigned short bof[CHUNK];     // 12 KB bucket of sorted[i]
    __shared__ int hist[1024];
    __shared__ int ex0[1024];
    __shared__ int cur[1024];
    __shared__ int gbase[1024];
    __shared__ int tsum[256];
    int b = blockIdx.x, t = threadIdx.x;
    int s0 = b * CHUNK;
    int cnt = E - s0; if (cnt > CHUNK) cnt = CHUNK;

    for (int i = t; i < 1024; i += 256) hist[i] = 0;
    __syncthreads();
    // pass 1: histogram
    for (int i = t; i < cnt; i += 256)
        atomicAdd(&hist[col[s0 + i] >> BKT_SH], 1);
    __syncthreads();
    // scan 1024 bins: thread t owns bins [4t, 4t+4)
    {
        int b0 = hist[4 * t], b1 = hist[4 * t + 1], b2 = hist[4 * t + 2], b3 = hist[4 * t + 3];
        int tot = b0 + b1 + b2 + b3;
        tsum[t] = tot;
        __syncthreads();
#pragma unroll
        for (int d = 1; d < 256; d <<= 1) {
            int x = (t >= d) ? tsum[t - d] : 0;
            __syncthreads();
            tsum[t] += (t >= d) ? x : 0;
            __syncthreads();
        }
        int ex = tsum[t] - tot;  // exclusive across thread groups
        ex0[4 * t] = ex;
        ex0[4 * t + 1] = ex + b0;
        ex0[4 * t + 2] = ex + b0 + b1;
        ex0[4 * t + 3] = ex + b0 + b1 + b2;
        cur[4 * t] = ex0[4 * t];
        cur[4 * t + 1] = ex0[4 * t + 1];
        cur[4 * t + 2] = ex0[4 * t + 2];
        cur[4 * t + 3] = ex0[4 * t + 3];
    }
    __syncthreads();
    // reserve: one atomic per non-empty (block,bucket); region base is fixed
    for (int i = t; i < 1024; i += 256)
        if (hist[i] > 0) gbase[i] = i * BKT_CAP + atomicAdd(&cursor[i], hist[i]);
    // pass 2: LDS sort by bucket (order within bucket irrelevant)
    for (int i = t; i < cnt; i += 256) {
        int c = col[s0 + i], r = row[s0 + i];
        int bkt = c >> BKT_SH;
        int p = atomicAdd(&cur[bkt], 1);
        sorted[p] = ((unsigned)(c & ((1 << BKT_SH) - 1)) << 17) | (unsigned)r;
        bof[p] = (unsigned short)bkt;
    }
    __syncthreads();
    // pass 3: run-coalesced global writes (guard against region overflow)
    for (int i = t; i < cnt; i += 256) {
        int bkt = bof[i];
        int pos = gbase[bkt] + (i - ex0[bkt]);
        if (pos < (bkt + 1) * BKT_CAP) bentries[pos] = sorted[i];
    }
}

// (B) per-bucket counting sort IN PLACE: bentries[b*CAP..] -> row indices
// sorted by destination node; emits start[node], cnt[node], dinv[node].
__global__ __launch_bounds__(256) void k_bucket_sort(
    unsigned* __restrict__ bentries, const int* __restrict__ cursor,
    int* __restrict__ start, int* __restrict__ cntarr,
    float* __restrict__ dinv, int N) {
    __shared__ int hist[128];
    __shared__ int incl[128];
    __shared__ int cur[128];
    __shared__ int rows[BKT_CAP];  // 16 KB
    int b = blockIdx.x, t = threadIdx.x;
    int base = b * BKT_CAP;
    int cnt = cursor[b];
    if (cnt > BKT_CAP) cnt = BKT_CAP;  // safety clamp (never expected)

    if (t < 128) hist[t] = 0;
    __syncthreads();
    for (int i = t; i < cnt; i += 256)
        atomicAdd(&hist[bentries[base + i] >> 17], 1);
    __syncthreads();
    if (t < 128) incl[t] = hist[t];
    __syncthreads();
#pragma unroll
    for (int d = 1; d < 128; d <<= 1) {
        int x = (t < 128 && t >= d) ? incl[t - d] : 0;
        __syncthreads();
        if (t < 128 && t >= d) incl[t] += x;
        __syncthreads();
    }
    if (t < 128) {
        int ex = incl[t] - hist[t];  // exclusive within bucket
        int node = (b << BKT_SH) + t;
        if (node < N) {
            start[node] = base + ex;
            cntarr[node] = hist[t];
            dinv[node] = rsqrtf((float)hist[t] + 1.0f);  // +1 self loop
        }
        cur[t] = ex;
    }
    __syncthreads();
    for (int i = t; i < cnt; i += 256) {
        unsigned en = bentries[base + i];
        int p = atomicAdd(&cur[en >> 17], 1);
        rows[p] = (int)(en & 0x1FFFF);
    }
    __syncthreads();
    for (int i = t; i < cnt; i += 256) bentries[base + i] = (unsigned)rows[i];
}

// Tiled GEMM + row scale, fp32 input, bf16 output.
// Block = 256 threads -> BM=128 rows x 64 cols. K chunked by BK=32.
__global__ __launch_bounds__(256) void k_gemm_f32in(
    const float* __restrict__ X, const float* __restrict__ W,
    const float* __restrict__ dinv, unsigned short* __restrict__ outb,
    int N, int K) {
    __shared__ float Xs[BK][BM + 4];
    __shared__ float Ws[BK][64];
    int t = threadIdx.x;
    int bm = blockIdx.x * BM;
    int tm = t >> 4, tn = t & 15;

    float acc[8][4];
#pragma unroll
    for (int i = 0; i < 8; ++i)
#pragma unroll
        for (int j = 0; j < 4; ++j) acc[i][j] = 0.f;

    for (int kb = 0; kb < K; kb += BK) {
#pragma unroll
        for (int it = 0; it < 4; ++it) {
            int r = (t >> 3) + 32 * it;       // 0..127
            int grow = bm + r;
            int k4 = t & 7;                   // float4 index within BK
            float4 v = make_float4(0.f, 0.f, 0.f, 0.f);
            if (grow < N) v = *(const float4*)(X + (size_t)grow * K + kb + k4 * 4);
            Xs[k4 * 4 + 0][r] = v.x;
            Xs[k4 * 4 + 1][r] = v.y;
            Xs[k4 * 4 + 2][r] = v.z;
            Xs[k4 * 4 + 3][r] = v.w;
        }
#pragma unroll
        for (int it = 0; it < 2; ++it) {
            int idx = t + 256 * it;           // 0..511 float4s
            ((float4*)Ws)[idx] = ((const float4*)(W + (size_t)kb * 64))[idx];
        }
        __syncthreads();
#pragma unroll
        for (int k = 0; k < BK; ++k) {
            float4 xa = *(const float4*)&Xs[k][tm * 8];
            float4 xb = *(const float4*)&Xs[k][tm * 8 + 4];
            float4 w = *(const float4*)&Ws[k][tn * 4];
            float xs[8] = {xa.x, xa.y, xa.z, xa.w, xb.x, xb.y, xb.z, xb.w};
#pragma unroll
            for (int i = 0; i < 8; ++i) {
                acc[i][0] = fmaf(xs[i], w.x, acc[i][0]);
                acc[i][1] = fmaf(xs[i], w.y, acc[i][1]);
                acc[i][2] = fmaf(xs[i], w.z, acc[i][2]);
                acc[i][3] = fmaf(xs[i], w.w, acc[i][3]);
            }
        }
        __syncthreads();
    }
#pragma unroll
    for (int i = 0; i < 8; ++i) {
        int grow = bm + tm * 8 + i;
        if (grow < N) {
            float s = dinv[grow];
            ushort4 v;
            v.x = f2bf(acc[i][0] * s);
            v.y = f2bf(acc[i][1] * s);
            v.z = f2bf(acc[i][2] * s);
            v.w = f2bf(acc[i][3] * s);
            *(ushort4*)(outb + (size_t)grow * 64 + tn * 4) = v;
        }
    }
}

// Tiled GEMM + row scale, bf16 input, bf16 output. Same tile shape.
__global__ __launch_bounds__(256) void k_gemm_bf16in(
    const unsigned short* __restrict__ Xb, const float* __restrict__ W,
    const float* __restrict__ dinv, unsigned short* __restrict__ outb,
    int N, int K) {
    __shared__ float Xs[BK][BM + 4];
    __shared__ float Ws[BK][64];
    int t = threadIdx.x;
    int bm = blockIdx.x * BM;
    int tm = t >> 4, tn = t & 15;

    float acc[8][4];
#pragma unroll
    for (int i = 0; i < 8; ++i)
#pragma unroll
        for (int j = 0; j < 4; ++j) acc[i][j] = 0.f;

    for (int kb = 0; kb < K; kb += BK) {
        // 128 rows x 32 k bf16 = 512 uint4 (8 bf16 each); 2 per thread
#pragma unroll
        for (int it = 0; it < 2; ++it) {
            int idx = t * 2 + it;             // 0..511
            int r = idx >> 2;                 // 0..127
            int q = idx & 3;                  // 16B chunk: k = q*8..q*8+8
            int grow = bm + r;
            uint4 v = make_uint4(0u, 0u, 0u, 0u);
            if (grow < N) v = *(const uint4*)(Xb + (size_t)grow * K + kb + q * 8);
            int k0 = q * 8;
            Xs[k0 + 0][r] = bflo(v.x); Xs[k0 + 1][r] = bfhi(v.x);
            Xs[k0 + 2][r] = bflo(v.y); Xs[k0 + 3][r] = bfhi(v.y);
            Xs[k0 + 4][r] = bflo(v.z); Xs[k0 + 5][r] = bfhi(v.z);
            Xs[k0 + 6][r] = bflo(v.w); Xs[k0 + 7][r] = bfhi(v.w);
        }
#pragma unroll
        for (int it = 0; it < 2; ++it) {
            int idx = t + 256 * it;           // 0..511 float4s
            ((float4*)Ws)[idx] = ((const float4*)(W + (size_t)kb * 64))[idx];
        }
        __syncthreads();
#pragma unroll
        for (int k = 0; k < BK; ++k) {
            float4 xa = *(const float4*)&Xs[k][tm * 8];
            float4 xb = *(const float4*)&Xs[k][tm * 8 + 4];
            float4 w = *(const float4*)&Ws[k][tn * 4];
            float xs[8] = {xa.x, xa.y, xa.z, xa.w, xb.x, xb.y, xb.z, xb.w};
#pragma unroll
            for (int i = 0; i < 8; ++i) {
                acc[i][0] = fmaf(xs[i], w.x, acc[i][0]);
                acc[i][1] = fmaf(xs[i], w.y, acc[i][1]);
                acc[i][2] = fmaf(xs[i], w.z, acc[i][2]);
                acc[i][3] = fmaf(xs[i], w.w, acc[i][3]);
            }
        }
        __syncthreads();
    }
#pragma unroll
    for (int i = 0; i < 8; ++i) {
        int grow = bm + tm * 8 + i;
        if (grow < N) {
            float s = dinv[grow];
            ushort4 v;
            v.x = f2bf(acc[i][0] * s);
            v.y = f2bf(acc[i][1] * s);
            v.z = f2bf(acc[i][2] * s);
            v.w = f2bf(acc[i][3] * s);
            *(ushort4*)(outb + (size_t)grow * 64 + tn * 4) = v;
        }
    }
}

// Gather-aggregate + fused postproc. 4 lanes/node; lane l owns channels
// [16l, 16l+16) as two contiguous uint4 (32B, same cacheline). fp32 accum.
// acc init = src[node] (self loop). Unroll 8/4/1 -> up to 16 uint4 + 8 index
// loads in flight per lane (2x the MLP of the 8-lane version, half the waves,
// half the redundant eros reads).
// mode 1: relu + bf16 out (dstq). mode 0: fp32 out (dstf).
__global__ __launch_bounds__(256) void k_gather(
    const uint4* __restrict__ srcq, const int* __restrict__ eros,
    const int* __restrict__ start, const int* __restrict__ cntarr,
    const float* __restrict__ dinv, const float* __restrict__ bias,
    float* __restrict__ dstf, uint4* __restrict__ dstq, int N, int mode) {
    int idx = blockIdx.x * 256 + threadIdx.x;
    int node = idx >> 2;
    if (node >= N) return;
    int l = idx & 3;

    float a[16];
    {
        uint4 s0 = srcq[(size_t)node * 8 + l * 2];      // self loop
        uint4 s1 = srcq[(size_t)node * 8 + l * 2 + 1];
        a[0] = bflo(s0.x); a[1] = bfhi(s0.x);
        a[2] = bflo(s0.y); a[3] = bfhi(s0.y);
        a[4] = bflo(s0.z); a[5] = bfhi(s0.z);
        a[6] = bflo(s0.w); a[7] = bfhi(s0.w);
        a[8] = bflo(s1.x); a[9] = bfhi(s1.x);
        a[10] = bflo(s1.y); a[11] = bfhi(s1.y);
        a[12] = bflo(s1.z); a[13] = bfhi(s1.z);
        a[14] = bflo(s1.w); a[15] = bfhi(s1.w);
    }

    int e = start[node];
    int eend = e + cntarr[node];
    for (; e + 8 <= eend; e += 8) {
        uint4 v0[8], v1[8];
#pragma unroll
        for (int j = 0; j < 8; ++j) {
            int r = eros[e + j];
            const uint4* p = srcq + (size_t)r * 8 + l * 2;
            v0[j] = p[0];
            v1[j] = p[1];
        }
#pragma unroll
        for (int j = 0; j < 8; ++j) {
            a[0] += bflo(v0[j].x); a[1] += bfhi(v0[j].x);
            a[2] += bflo(v0[j].y); a[3] += bfhi(v0[j].y);
            a[4] += bflo(v0[j].z); a[5] += bfhi(v0[j].z);
            a[6] += bflo(v0[j].w); a[7] += bfhi(v0[j].w);
            a[8] += bflo(v1[j].x); a[9] += bfhi(v1[j].x);
            a[10] += bflo(v1[j].y); a[11] += bfhi(v1[j].y);
            a[12] += bflo(v1[j].z); a[13] += bfhi(v1[j].z);
            a[14] += bflo(v1[j].w); a[15] += bfhi(v1[j].w);
        }
    }
    for (; e + 4 <= eend; e += 4) {
        uint4 v0[4], v1[4];
#pragma unroll
        for (int j = 0; j < 4; ++j) {
            int r = eros[e + j];
            const uint4* p = srcq + (size_t)r * 8 + l * 2;
            v0[j] = p[0];
            v1[j] = p[1];
        }
#pragma unroll
        for (int j = 0; j < 4; ++j) {
            a[0] += bflo(v0[j].x); a[1] += bfhi(v0[j].x);
            a[2] += bflo(v0[j].y); a[3] += bfhi(v0[j].y);
            a[4] += bflo(v0[j].z); a[5] += bfhi(v0[j].z);
            a[6] += bflo(v0[j].w); a[7] += bfhi(v0[j].w);
            a[8] += bflo(v1[j].x); a[9] += bfhi(v1[j].x);
            a[10] += bflo(v1[j].y); a[11] += bfhi(v1[j].y);
            a[12] += bflo(v1[j].z); a[13] += bfhi(v1[j].z);
            a[14] += bflo(v1[j].w); a[15] += bfhi(v1[j].w);
        }
    }
    for (; e < eend; ++e) {
        int r = eros[e];
        const uint4* p = srcq + (size_t)r * 8 + l * 2;
        uint4 v0 = p[0], v1 = p[1];
        a[0] += bflo(v0.x); a[1] += bfhi(v0.x);
        a[2] += bflo(v0.y); a[3] += bfhi(v0.y);
        a[4] += bflo(v0.z); a[5] += bfhi(v0.z);
        a[6] += bflo(v0.w); a[7] += bfhi(v0.w);
        a[8] += bflo(v1.x); a[9] += bfhi(v1.x);
        a[10] += bflo(v1.y); a[11] += bfhi(v1.y);
        a[12] += bflo(v1.z); a[13] += bfhi(v1.z);
        a[14] += bflo(v1.w); a[15] += bfhi(v1.w);
    }
    float sc = dinv[node];
    const float4* bp = (const float4*)bias;
#pragma unroll
    for (int q = 0; q < 4; ++q) {
        float4 bq = bp[l * 4 + q];
        a[q * 4 + 0] = a[q * 4 + 0] * sc + bq.x;
        a[q * 4 + 1] = a[q * 4 + 1] * sc + bq.y;
        a[q * 4 + 2] = a[q * 4 + 2] * sc + bq.z;
        a[q * 4 + 3] = a[q * 4 + 3] * sc + bq.w;
    }
    if (mode) {  // relu + bf16 pack
#pragma unroll
        for (int i = 0; i < 16; ++i) a[i] = fmaxf(a[i], 0.f);
        uint4 o0, o1;
        o0.x = (unsigned)f2bf(a[0]) | ((unsigned)f2bf(a[1]) << 16);
        o0.y = (unsigned)f2bf(a[2]) | ((unsigned)f2bf(a[3]) << 16);
        o0.z = (unsigned)f2bf(a[4]) | ((unsigned)f2bf(a[5]) << 16);
        o0.w = (unsigned)f2bf(a[6]) | ((unsigned)f2bf(a[7]) << 16);
        o1.x = (unsigned)f2bf(a[8]) | ((unsigned)f2bf(a[9]) << 16);
        o1.y = (unsigned)f2bf(a[10]) | ((unsigned)f2bf(a[11]) << 16);
        o1.z = (unsigned)f2bf(a[12]) | ((unsigned)f2bf(a[13]) << 16);
        o1.w = (unsigned)f2bf(a[14]) | ((unsigned)f2bf(a[15]) << 16);
        dstq[(size_t)node * 8 + l * 2] = o0;
        dstq[(size_t)node * 8 + l * 2 + 1] = o1;
    } else {
        float4* d = (float4*)(dstf + (size_t)node * 64 + l * 16);
        d[0] = make_float4(a[0], a[1], a[2], a[3]);
        d[1] = make_float4(a[4], a[5], a[6], a[7]);
        d[2] = make_float4(a[8], a[9], a[10], a[11]);
        d[3] = make_float4(a[12], a[13], a[14], a[15]);
    }
}

extern "C" void kernel_launch(void* const* d_in, const int* in_sizes, int n_in,
                              void* d_out, int out_size, void* d_ws, size_t ws_size,
                              hipStream_t stream) {
    const float* x = (const float*)d_in[0];
    const int* ei = (const int*)d_in[1];  // int32 per harness contract, [2, E]
    const float* W1 = (const float*)d_in[2];
    const float* b1 = (const float*)d_in[3];
    const float* W2 = (const float*)d_in[4];
    const float* b2 = (const float*)d_in[5];

    int N = in_sizes[0] / 128;  // 100000
    int E = in_sizes[1] / 2;    // 1600000
    const int* row = ei;
    const int* col = ei + E;
    int nb = (N + (1 << BKT_SH) - 1) >> BKT_SH;  // 782 buckets

    char* ws = (char*)d_ws;
    int* cursor = (int*)ws;                          // nb ints @ 0
    int* start = (int*)(ws + (1 << 16));             // N ints @ 64 KB
    int* cntarr = (int*)(ws + (1 << 19));            // N ints @ 512 KB
    float* dinv = (float*)(ws + 960 * 1024);         // N floats @ 960 KB
    unsigned* bentries = (unsigned*)(ws + (2 << 20));    // nb*CAP u32 @ 2 MB (12.8 MB)
    unsigned short* Ab = (unsigned short*)(ws + (15 << 20));  // N*64 bf16 @ 15 MB (12.8 MB)
    unsigned short* Hb = (unsigned short*)d_out;     // bf16 h2 scratch in d_out
    float* OUTF = (float*)d_out;                     // final fp32 output

    int gemmblk = (N + BM - 1) / BM;       // 782
    int binblk = (E + CHUNK - 1) / CHUNK;  // 261
    int gblk = (N * 4 + 255) / 256;        // 1563

    // --- CSR build (padded buckets; once, shared by both layers) ---
    k_zero_i<<<(nb + 255) / 256, 256, 0, stream>>>(cursor, nb);
    k_bin<<<binblk, 256, 0, stream>>>(row, col, cursor, bentries, E);
    k_bucket_sort<<<nb, 256, 0, stream>>>(bentries, cursor, start, cntarr, dinv, N);

    // Layer 1: Ab = bf16((X@W1)*dinv); Hb = bf16(relu(gather(Ab)*dinv + b1))
    k_gemm_f32in<<<gemmblk, 256, 0, stream>>>(x, W1, dinv, Ab, N, 128);
    k_gather<<<gblk, 256, 0, stream>>>((const uint4*)Ab, (const int*)bentries,
                                       start, cntarr, dinv, b1,
                                       nullptr, (uint4*)Hb, N, 1);

    // Layer 2: Ab = bf16((Hb@W2)*dinv); d_out = gather(Ab)*dinv + b2 (fp32)
    k_gemm_bf16in<<<gemmblk, 256, 0, stream>>>(Hb, W2, dinv, Ab, N, 64);
    k_gather<<<gblk, 256, 0, stream>>>((const uint4*)Ab, (const int*)bentries,
                                       start, cntarr, dinv, b2,
                                       OUTF, nullptr, N, 0);
}